// Round 23
// baseline (244.367 us; speedup 1.0000x reference)
//
#include <hip/hip_runtime.h>
#include <math.h>

#define HW 262144   // 512*512

__device__ __forceinline__ int clip511f(float t) { return (int)fminf(fmaxf(t, 0.0f), 511.0f); }

// Oracle tree P=2305: all-f32, norm = t*(1/255.5), strict grid chain (no fma),
// flat source-order bilinear, no-fma dots/norms, pairwise simsum ((s0+s1)+(s2+s3))+s0.
__global__ __launch_bounds__(256) void pd_kernel(
    const float* __restrict__ rf,  const float* __restrict__ nrm,
    const float* __restrict__ dv,  const float* __restrict__ intri,
    const float* __restrict__ w0, const float* __restrict__ s0, const float* __restrict__ b0,
    const float* __restrict__ w1, const float* __restrict__ s1, const float* __restrict__ b1,
    const float* __restrict__ w2, const float* __restrict__ b2,
    float* __restrict__ out)
{
#pragma clang fp contract(off)
    int pid = blockIdx.x * 256 + threadIdx.x;   // 0 .. 524287
    int b = pid >> 18;
    int r = pid & (HW - 1);
    int y = r >> 9;
    int x = r & 511;

    float fx = intri[b * 9 + 0], cx = intri[b * 9 + 2];
    float fy = intri[b * 9 + 4], cy = intri[b * 9 + 5];

    const float* nb = nrm + (size_t)(b * 3) * HW;
    const float* fb = rf  + (size_t)(b * 32) * HW;

    float nx = nb[r], ny = nb[HW + r], nz = nb[2 * HW + r];
    float nbn = sqrtf((nx * nx + ny * ny) + nz * nz);

    const float RCP = (float)(1.0 / 255.5);   // recip-mul (XLA div-by-const fold)
    const int OY[4] = {1, 0, 0, 0};
    const int OX[4] = {0, -1, 0, 1};

    float u[5], v[5], sim[5];
    double F[5];

    for (int n = 0; n < 4; ++n) {
        // ---- f32 grid chain: strict form with recip-mul norm ----
        float qx = (float)(x + OX[n]) * RCP;
        float qy = (float)(y + OY[n]) * RCP;
        float gpx = (qx - 1.0f) + 1.0f;
        float gpy = (qy - 1.0f) + 1.0f;
        float ix = ((gpx * 512.0f) - 1.0f) * 0.5f;
        float iy = ((gpy * 512.0f) - 1.0f) * 0.5f;
        float x0f = floorf(ix), y0f = floorf(iy);
        float wx = ix - x0f,  wy = iy - y0f;
        int x0 = clip511f(x0f), x1 = clip511f(x0f + 1.0f);
        int y0 = clip511f(y0f), y1 = clip511f(y0f + 1.0f);
        float omx = 1.0f - wx, omy = 1.0f - wy;

        long long i00 = (long long)y0 * 512 + x0, i01 = (long long)y0 * 512 + x1;
        long long i10 = (long long)y1 * 512 + x0, i11 = (long long)y1 * 512 + x1;

        // ---- flat source-order f32 bilinear: ((A+B)+C)+D ----
        // coordinate image (values = clipped int coords)
        {
            float m00 = (float)x0 * omx, m01 = (float)x1 * wx;
            float m10 = (float)x0 * omx, m11 = (float)x1 * wx;
            float A = m00 * omy, B = m01 * omy, C = m10 * wy, D = m11 * wy;
            float xs_ = ((A + B) + C) + D;
            float n00 = (float)y0 * omx, n01 = (float)y0 * wx;
            float n10 = (float)y1 * omx, n11 = (float)y1 * wx;
            float A2 = n00 * omy, B2 = n01 * omy, C2 = n10 * wy, D2 = n11 * wy;
            float ys_ = ((A2 + B2) + C2) + D2;
            u[n] = (xs_ - cx) / fx;
            v[n] = (ys_ - cy) / fy;
        }

        // normals bilinear (f32, same tree)
        float nsx, nsy, nsz;
        {
            float m00 = nb[i00] * omx, m01 = nb[i01] * wx;
            float m10 = nb[i10] * omx, m11 = nb[i11] * wx;
            nsx = ((m00 * omy + m01 * omy) + m10 * wy) + m11 * wy;
            float p00 = nb[HW + i00] * omx, p01 = nb[HW + i01] * wx;
            float p10 = nb[HW + i10] * omx, p11 = nb[HW + i11] * wx;
            nsy = ((p00 * omy + p01 * omy) + p10 * wy) + p11 * wy;
            float q00 = nb[2*HW + i00] * omx, q01 = nb[2*HW + i01] * wx;
            float q10 = nb[2*HW + i10] * omx, q11 = nb[2*HW + i11] * wx;
            nsz = ((q00 * omy + q01 * omy) + q10 * wy) + q11 * wy;
        }

        float dot = (nsx * nx + nsy * ny) + nsz * nz;
        float na  = sqrtf((nsx * nsx + nsy * nsy) + nsz * nsz);
        sim[n] = dot / (fmaxf(na, 1e-8f) * fmaxf(nbn, 1e-8f));

        // feature channel-sum: smooth -> f64
        double F00 = 0.0, F01 = 0.0, F10 = 0.0, F11 = 0.0;
        for (int c = 0; c < 32; ++c) {
            const float* p = fb + (size_t)c * HW;
            F00 += (double)p[i00]; F01 += (double)p[i01];
            F10 += (double)p[i10]; F11 += (double)p[i11];
        }
        double Wx0 = (double)omx, Wx1 = (double)wx, Wy0 = (double)omy, Wy1 = (double)wy;
        F[n] = ((F00 * Wx0) * Wy0 + (F01 * Wx1) * Wy0)
             + ((F10 * Wx0) * Wy1 + (F11 * Wx1) * Wy1);
    }
    u[4] = u[0]; v[4] = v[0]; sim[4] = sim[0]; F[4] = F[0];

    // pairwise simsum (ssord=1): ((s0+s1)+(s2+s3))+s4, s4==s0
    float ss = ((sim[0] + sim[1]) + (sim[2] + sim[3])) + sim[4];

    // den/w in exact f32 (no fma, left-assoc)
    float num = (nx * u[2] + ny * v[2]) + nz;
    float wv[5];
    for (int n = 0; n < 5; ++n) {
        float den = (nx * u[n] + ny * v[n]) + nz;
        if (fabsf(den) < 1e-8f) den = (den < 0.0f) ? -1e-8f : 1e-8f;
        float w_ = num / den;
        if (!isfinite(w_)) w_ = 1.0f;
        wv[n] = w_;
    }

    // ---- smooth downstream in f64 using the exact-f32 sim/ss/w ----
    double qd[5];
    for (int n = 0; n < 5; ++n)
        qd[n] = ((double)sim[n] / (double)ss) * F[n];

    double dvv[8];
    for (int d = 0; d < 8; ++d)
        dvv[d] = (double)dv[(size_t)(b * 8 + d) * HW + r];

    double sv[8];
    for (int dp = 0; dp < 8; ++dp) {
        double acc = 0.0;
        for (int n = 0; n < 5; ++n) {
            int flat = n * 8 + dp;
            acc += qd[n] * ((double)wv[flat % 5] * dvv[flat / 5]);
        }
        sv[dp] = acc / 32.0;
    }

    double vwmax = -1.0;
    for (int dp = 0; dp < 8; ++dp) {
        double h0[16];
        for (int k = 0; k < 16; ++k)
            h0[k] = fmax((double)w0[k] * sv[dp] * (double)s0[k] + (double)b0[k], 0.0);
        double lg = (double)b2[0];
        for (int j = 0; j < 8; ++j) {
            double a1 = 0.0;
            for (int k = 0; k < 16; ++k)
                a1 += (double)w1[j * 16 + k] * h0[k];
            double h1 = fmax(a1 * (double)s1[j] + (double)b1[j], 0.0);
            lg += (double)w2[j] * h1;
        }
        double sg = 1.0 / (1.0 + exp(-lg));
        vwmax = fmax(vwmax, sg);
    }

    for (int dp = 0; dp < 8; ++dp)
        out[(size_t)(b * 8 + dp) * HW + r] = (float)(sv[dp] * vwmax);
}

extern "C" void kernel_launch(void* const* d_in, const int* in_sizes, int n_in,
                              void* d_out, int out_size, void* d_ws, size_t ws_size,
                              hipStream_t stream) {
    const float* rf    = (const float*)d_in[0];
    const float* nrm   = (const float*)d_in[1];
    const float* dv    = (const float*)d_in[2];
    const float* intri = (const float*)d_in[3];
    const float* w0    = (const float*)d_in[4];
    const float* s0    = (const float*)d_in[5];
    const float* b0    = (const float*)d_in[6];
    const float* w1    = (const float*)d_in[7];
    const float* s1    = (const float*)d_in[8];
    const float* b1    = (const float*)d_in[9];
    const float* w2    = (const float*)d_in[10];
    const float* b2    = (const float*)d_in[11];
    float* out = (float*)d_out;

    pd_kernel<<<2048, 256, 0, stream>>>(rf, nrm, dv, intri,
                                        w0, s0, b0, w1, s1, b1, w2, b2, out);
}

// Round 24
// 58.824 us; speedup vs baseline: 4.1542x; 4.1542x over previous
//
#include <hip/hip_runtime.h>
#include <math.h>

#define HW 262144   // 512*512

__device__ __forceinline__ int clip511f(float t) { return (int)fminf(fmaxf(t, 0.0f), 511.0f); }

// ---------------- Kernel 1: Fsum[b,y,x] = sum_c ref_feature[b,c,y,x] ----------------
__global__ __launch_bounds__(256) void fsum_kernel(const float* __restrict__ rf,
                                                   float* __restrict__ fsum) {
    int t = blockIdx.x * 256 + threadIdx.x;        // 0 .. 131071
    int b = t >> 16;
    int q = t & 65535;
    const float4* src = reinterpret_cast<const float4*>(rf) + (size_t)(b * 32) * 65536 + q;
    float4 acc = make_float4(0.f, 0.f, 0.f, 0.f);
    #pragma unroll
    for (int c = 0; c < 32; ++c) {
        float4 v = src[(size_t)c * 65536];
        acc.x += v.x; acc.y += v.y; acc.z += v.z; acc.w += v.w;
    }
    reinterpret_cast<float4*>(fsum)[t] = acc;
}

// Exact oracle axis chain (tree P=2305): q = t*(1/255.5); strict (-1,+1) roundtrip;
// ix = ((gp*512)-1)*0.5; floor; wx = ix - x0.
struct Axis { float wx, om; int c0, c1; };
__device__ __forceinline__ Axis axis_eval(int t_int) {
#pragma clang fp contract(off)
    const float RCP = (float)(1.0 / 255.5);
    float q = (float)t_int * RCP;
    float gp = (q - 1.0f) + 1.0f;
    float ix = ((gp * 512.0f) - 1.0f) * 0.5f;
    float x0 = floorf(ix);
    Axis a;
    a.wx = ix - x0;
    a.om = 1.0f - a.wx;
    a.c0 = clip511f(x0);
    a.c1 = clip511f(x0 + 1.0f);
    return a;
}

// ---------------- Kernel 2: patch kernel, all-f32 ----------------
__global__ __launch_bounds__(256) void patch_kernel(
    const float* __restrict__ nrm, const float* __restrict__ dv,
    const float* __restrict__ intri, const float* __restrict__ fsum,
    const float* __restrict__ w0, const float* __restrict__ s0, const float* __restrict__ b0,
    const float* __restrict__ w1, const float* __restrict__ s1, const float* __restrict__ b1,
    const float* __restrict__ w2, const float* __restrict__ b2,
    float* __restrict__ out)
{
    // stage MLP weights: [0,16) w0, [16,32) s0, [32,48) b0, [48,176) w1,
    // [176,184) s1, [184,192) b1, [192,200) w2, [200] b2
    __shared__ float sW[201];
    int tid = threadIdx.x;
    if (tid < 201) {
        float vv;
        if      (tid < 16)  vv = w0[tid];
        else if (tid < 32)  vv = s0[tid - 16];
        else if (tid < 48)  vv = b0[tid - 32];
        else if (tid < 176) vv = w1[tid - 48];
        else if (tid < 184) vv = s1[tid - 176];
        else if (tid < 192) vv = b1[tid - 184];
        else if (tid < 200) vv = w2[tid - 192];
        else                vv = b2[0];
        sW[tid] = vv;
    }
    __syncthreads();

    int pid = blockIdx.x * 256 + tid;   // 0 .. 524287
    int b = pid >> 18;
    int r = pid & (HW - 1);
    int y = r >> 9;
    int x = r & 511;

    float fx = intri[b * 9 + 0], cx = intri[b * 9 + 2];
    float fy = intri[b * 9 + 4], cy = intri[b * 9 + 5];

    const float* nb = nrm  + (size_t)(b * 3) * HW;
    const float* fb = fsum + (size_t)b * HW;

    float nx = nb[r], ny = nb[HW + r], nz = nb[2 * HW + r];

    float u[5], v[5], sim[5], F[5];
    float ss, num, wv[5];
    {
#pragma clang fp contract(off)
        float nbn = sqrtf((nx * nx + ny * ny) + nz * nz);

        // shared axes: x-1, x, x+1 ; y, y+1
        Axis axm = axis_eval(x - 1);
        Axis ax0 = axis_eval(x);
        Axis axp = axis_eval(x + 1);
        Axis ay0 = axis_eval(y);
        Axis ayp = axis_eval(y + 1);

        // taps (oy,ox): n0=(1,0)->(ax0,ayp), n1=(0,-1)->(axm,ay0),
        //               n2=(0,0)->(ax0,ay0), n3=(0,1)->(axp,ay0)
        const Axis* AX[4] = { &ax0, &axm, &ax0, &axp };
        const Axis* AY[4] = { &ayp, &ay0, &ay0, &ay0 };

        for (int n = 0; n < 4; ++n) {
            const Axis& ax = *AX[n];
            const Axis& ay = *AY[n];
            float wxf = ax.wx, omx = ax.om;
            float wyf = ay.wx, omy = ay.om;
            int x0 = ax.c0, x1 = ax.c1, y0 = ay.c0, y1 = ay.c1;

            int i00 = y0 * 512 + x0, i01 = y0 * 512 + x1;
            int i10 = y1 * 512 + x0, i11 = y1 * 512 + x1;

            // xy coordinate sample — exact flat tree
            {
                float m00 = (float)x0 * omx, m01 = (float)x1 * wxf;
                float m10 = (float)x0 * omx, m11 = (float)x1 * wxf;
                float A = m00 * omy, B = m01 * omy, C = m10 * wyf, D = m11 * wyf;
                float xs_ = ((A + B) + C) + D;
                float n00 = (float)y0 * omx, n01 = (float)y0 * wxf;
                float n10 = (float)y1 * omx, n11 = (float)y1 * wxf;
                float A2 = n00 * omy, B2 = n01 * omy, C2 = n10 * wyf, D2 = n11 * wyf;
                float ys_ = ((A2 + B2) + C2) + D2;
                u[n] = (xs_ - cx) / fx;
                v[n] = (ys_ - cy) / fy;
            }

            // normals bilinear — exact flat tree
            float nsx, nsy, nsz;
            {
                float m00 = nb[i00] * omx, m01 = nb[i01] * wxf;
                float m10 = nb[i10] * omx, m11 = nb[i11] * wxf;
                nsx = ((m00 * omy + m01 * omy) + m10 * wyf) + m11 * wyf;
                float p00 = nb[HW + i00] * omx, p01 = nb[HW + i01] * wxf;
                float p10 = nb[HW + i10] * omx, p11 = nb[HW + i11] * wxf;
                nsy = ((p00 * omy + p01 * omy) + p10 * wyf) + p11 * wyf;
                float q00 = nb[2*HW + i00] * omx, q01 = nb[2*HW + i01] * wxf;
                float q10 = nb[2*HW + i10] * omx, q11 = nb[2*HW + i11] * wxf;
                nsz = ((q00 * omy + q01 * omy) + q10 * wyf) + q11 * wyf;
            }

            float dot = (nsx * nx + nsy * ny) + nsz * nz;
            float na  = sqrtf((nsx * nsx + nsy * nsy) + nsz * nsz);
            sim[n] = dot / (fmaxf(na, 1e-8f) * fmaxf(nbn, 1e-8f));

            // F from precomputed channel-sum (smooth)
            {
                float m00 = fb[i00] * omx, m01 = fb[i01] * wxf;
                float m10 = fb[i10] * omx, m11 = fb[i11] * wxf;
                F[n] = ((m00 * omy + m01 * omy) + m10 * wyf) + m11 * wyf;
            }
        }
        u[4] = u[0]; v[4] = v[0]; sim[4] = sim[0]; F[4] = F[0];

        // pairwise simsum: ((s0+s1)+(s2+s3))+s4
        ss = ((sim[0] + sim[1]) + (sim[2] + sim[3])) + sim[4];

        num = (nx * u[2] + ny * v[2]) + nz;
        for (int n = 0; n < 5; ++n) {
            float den = (nx * u[n] + ny * v[n]) + nz;
            if (fabsf(den) < 1e-8f) den = (den < 0.0f) ? -1e-8f : 1e-8f;
            float w_ = num / den;
            if (!isfinite(w_)) w_ = 1.0f;
            wv[n] = w_;
        }
    }

    // smooth contraction (f32, FMA ok)
    float qv[5];
    #pragma unroll
    for (int n = 0; n < 5; ++n) qv[n] = (sim[n] / ss) * F[n];

    size_t dvbase = (size_t)(b * 8) * HW + (size_t)r;
    float dvv[8];
    #pragma unroll
    for (int d = 0; d < 8; ++d) dvv[d] = dv[dvbase + (size_t)d * HW];

    float sv[8];
    #pragma unroll
    for (int dp = 0; dp < 8; ++dp) {
        float acc = 0.0f;
        #pragma unroll
        for (int n = 0; n < 5; ++n) {
            const int flat = n * 8 + dp;
            acc += qv[n] * (wv[flat % 5] * dvv[flat / 5]);
        }
        sv[dp] = acc * 0.03125f;
    }

    // MLP, d=8 vectorized (f32, FMA ok)
    float accm[8][8];
    #pragma unroll
    for (int j = 0; j < 8; ++j)
        #pragma unroll
        for (int d = 0; d < 8; ++d) accm[j][d] = 0.0f;

    #pragma unroll
    for (int k = 0; k < 16; ++k) {
        float w0k = sW[k], s0k = sW[16 + k], b0k = sW[32 + k];
        float h0[8];
        #pragma unroll
        for (int d = 0; d < 8; ++d)
            h0[d] = fmaxf((w0k * sv[d]) * s0k + b0k, 0.0f);
        #pragma unroll
        for (int j = 0; j < 8; ++j) {
            float w1jk = sW[48 + j * 16 + k];
            #pragma unroll
            for (int d = 0; d < 8; ++d) accm[j][d] += w1jk * h0[d];
        }
    }

    float b2v = sW[200];
    float lg[8];
    #pragma unroll
    for (int d = 0; d < 8; ++d) lg[d] = b2v;
    #pragma unroll
    for (int j = 0; j < 8; ++j) {
        float s1j = sW[176 + j], b1j = sW[184 + j], w2j = sW[192 + j];
        #pragma unroll
        for (int d = 0; d < 8; ++d) {
            float h1 = fmaxf(accm[j][d] * s1j + b1j, 0.0f);
            lg[d] += w2j * h1;
        }
    }
    float mx = lg[0];
    #pragma unroll
    for (int d = 1; d < 8; ++d) mx = fmaxf(mx, lg[d]);
    float vw = 1.0f / (1.0f + expf(-mx));   // max_d sigmoid == sigmoid(max_d)

    #pragma unroll
    for (int d = 0; d < 8; ++d)
        out[dvbase + (size_t)d * HW] = sv[d] * vw;
}

extern "C" void kernel_launch(void* const* d_in, const int* in_sizes, int n_in,
                              void* d_out, int out_size, void* d_ws, size_t ws_size,
                              hipStream_t stream) {
    const float* rf    = (const float*)d_in[0];
    const float* nrm   = (const float*)d_in[1];
    const float* dv    = (const float*)d_in[2];
    const float* intri = (const float*)d_in[3];
    const float* w0    = (const float*)d_in[4];
    const float* s0    = (const float*)d_in[5];
    const float* b0    = (const float*)d_in[6];
    const float* w1    = (const float*)d_in[7];
    const float* s1    = (const float*)d_in[8];
    const float* b1    = (const float*)d_in[9];
    const float* w2    = (const float*)d_in[10];
    const float* b2    = (const float*)d_in[11];
    float* out  = (float*)d_out;
    float* fsum = (float*)d_ws;   // 2 MB scratch

    fsum_kernel<<<512, 256, 0, stream>>>(rf, fsum);
    patch_kernel<<<2048, 256, 0, stream>>>(nrm, dv, intri, fsum,
                                           w0, s0, b0, w1, s1, b1, w2, b2, out);
}